// Round 1
// baseline (372.955 us; speedup 1.0000x reference)
//
#include <hip/hip_runtime.h>
#include <hip/hip_bf16.h>

typedef __bf16 bf16_t;
typedef __bf16 bf16x8 __attribute__((ext_vector_type(8)));
typedef float f32x4 __attribute__((ext_vector_type(4)));

#define NV 8000   // D*H*W
#define QB 125    // NV / 64

// ---------------------------------------------------------------------------
// Kernel 1: fused 1x1x1 convs.  x[b][c][n] (f32) -> Q[b][n][k], K[b][n][k]
// (bf16, Q pre-scaled by 1/sqrt(64)*log2e), Vt[b][v][n] (bf16).
// One block per (b, 64-voxel tile). Weights read via wave-uniform s_loads.
// ---------------------------------------------------------------------------
__global__ __launch_bounds__(256) void qkv_kernel(
    const float* __restrict__ x,
    const float* __restrict__ wq, const float* __restrict__ bq,
    const float* __restrict__ wk, const float* __restrict__ bk,
    const float* __restrict__ wv, const float* __restrict__ bv,
    bf16_t* __restrict__ Q, bf16_t* __restrict__ Kr, bf16_t* __restrict__ Vt)
{
    __shared__ float xl[64 * 64];   // [c][n]
    const int tid = threadIdx.x;
    const int b  = blockIdx.x / QB;
    const int n0 = (blockIdx.x % QB) * 64;

    // stage x tile, coalesced float4
    #pragma unroll
    for (int it = 0; it < 4; ++it) {
        int i = tid + it * 256;          // float4 index 0..1023
        int c = i >> 4, seg = i & 15;
        *reinterpret_cast<float4*>(&xl[c * 64 + seg * 4]) =
            *reinterpret_cast<const float4*>(&x[((size_t)b * 64 + c) * NV + n0 + seg * 4]);
    }
    __syncthreads();

    const int n = tid & 63;
    const int ksub = __builtin_amdgcn_readfirstlane(threadIdx.x >> 6); // wave-uniform

    float xcol[64];
    #pragma unroll
    for (int c = 0; c < 64; ++c) xcol[c] = xl[c * 64 + n];

    const float QSCALE = 0.125f * 1.44269504088896f;  // 1/sqrt(ck) * log2(e)
    const size_t qrow = ((size_t)b * NV + n0 + n) * 64;

    #pragma unroll 1
    for (int j = 0; j < 16; ++j) {
        const int k = ksub * 16 + j;
        const float* __restrict__ wrq = wq + k * 64;
        const float* __restrict__ wrk = wk + k * 64;
        const float* __restrict__ wrv = wv + k * 64;
        float aq = 0.f, ak = 0.f, av = 0.f;
        #pragma unroll
        for (int c = 0; c < 64; ++c) {
            aq = fmaf(wrq[c], xcol[c], aq);
            ak = fmaf(wrk[c], xcol[c], ak);
            av = fmaf(wrv[c], xcol[c], av);
        }
        Q [qrow + k] = (bf16_t)((aq + bq[k]) * QSCALE);
        Kr[qrow + k] = (bf16_t)(ak + bk[k]);
        Vt[((size_t)b * 64 + k) * NV + n0 + n] = (bf16_t)(av + bv[k]);
    }
}

// ---------------------------------------------------------------------------
// Kernel 2: flash attention. One block per (b, 64 Q rows); 4 waves x 16 rows.
// K,Vt tiles staged to XOR-swizzled LDS; S = Q*K^T via mfma 16x16x32 bf16;
// online softmax in exp2 domain (scale folded into Q); P -> LDS -> PV mfma.
// O[b][n][v] written as f32 (pre-divided by row sum l).
// ---------------------------------------------------------------------------
__global__ __launch_bounds__(256) void attn_kernel(
    const bf16_t* __restrict__ Q, const bf16_t* __restrict__ Kr,
    const bf16_t* __restrict__ Vt, float* __restrict__ O)
{
    __shared__ __align__(16) char kt[64 * 128];
    __shared__ __align__(16) char vt[64 * 128];
    __shared__ __align__(16) char pt[64 * 128];

    const int tid  = threadIdx.x;
    const int b    = blockIdx.x / QB;
    const int q0   = (blockIdx.x % QB) * 64;
    const int w    = tid >> 6;      // wave 0..3 -> Q rows w*16..+15
    const int lane = tid & 63;
    const int g    = lane >> 4;     // 16-lane group
    const int lr   = lane & 15;

    // Q fragments held in registers for the whole K loop
    bf16x8 qa0, qa1;
    {
        const size_t qbase = ((size_t)b * NV + q0 + w * 16 + lr) * 64;
        qa0 = *reinterpret_cast<const bf16x8*>(&Q[qbase + 8 * g]);
        qa1 = *reinterpret_cast<const bf16x8*>(&Q[qbase + 32 + 8 * g]);
    }

    const f32x4 zero4 = {0.f, 0.f, 0.f, 0.f};
    f32x4 oacc[4];
    float m[4], l[4];
    #pragma unroll
    for (int r = 0; r < 4; ++r) { m[r] = -1e30f; l[r] = 0.f; }
    #pragma unroll
    for (int vf = 0; vf < 4; ++vf) oacc[vf] = zero4;

    const size_t kbase = (size_t)b * NV * 64;
    const size_t vbase = (size_t)b * 64 * NV;

    for (int t = 0; t < 125; ++t) {
        const int m0 = t * 64;
        __syncthreads();  // previous iter's K/V consumers done
        // stage K and Vt tiles (64x64 bf16 each), 16B chunks, XOR swizzle
        #pragma unroll
        for (int it = 0; it < 2; ++it) {
            int i = tid + it * 256;          // chunk index 0..511
            int row = i >> 3, ch = i & 7;
            int dst = row * 128 + ((ch * 16) ^ ((row & 7) << 4));
            *reinterpret_cast<uint4*>(kt + dst) =
                *reinterpret_cast<const uint4*>(&Kr[kbase + (size_t)(m0 + row) * 64 + ch * 8]);
            *reinterpret_cast<uint4*>(vt + dst) =
                *reinterpret_cast<const uint4*>(&Vt[vbase + (size_t)row * NV + m0 + ch * 8]);
        }
        __syncthreads();

        // S = Q K^T : 4 column fragments of 16x16, K-dim 64 in 2 steps
        f32x4 s[4];
        #pragma unroll
        for (int cf = 0; cf < 4; ++cf) {
            s[cf] = zero4;
            const int row  = cf * 16 + lr;
            const int roff = row * 128;
            const int swz  = (row & 7) << 4;
            s[cf] = __builtin_amdgcn_mfma_f32_16x16x32_bf16(
                qa0, *reinterpret_cast<const bf16x8*>(kt + roff + ((16 * g) ^ swz)),
                s[cf], 0, 0, 0);
            s[cf] = __builtin_amdgcn_mfma_f32_16x16x32_bf16(
                qa1, *reinterpret_cast<const bf16x8*>(kt + roff + ((64 + 16 * g) ^ swz)),
                s[cf], 0, 0, 0);
        }

        // online softmax (exp2 domain; rows live in 16-lane groups)
        #pragma unroll
        for (int r = 0; r < 4; ++r) {
            float mx = fmaxf(fmaxf(s[0][r], s[1][r]), fmaxf(s[2][r], s[3][r]));
            #pragma unroll
            for (int off = 1; off < 16; off <<= 1)
                mx = fmaxf(mx, __shfl_xor(mx, off, 64));
            const float mn   = fmaxf(m[r], mx);
            const float corr = exp2f(m[r] - mn);
            m[r] = mn;
            float ps = 0.f;
            #pragma unroll
            for (int cf = 0; cf < 4; ++cf) {
                float p = exp2f(s[cf][r] - mn);
                s[cf][r] = p;
                ps += p;
            }
            #pragma unroll
            for (int off = 1; off < 16; off <<= 1)
                ps += __shfl_xor(ps, off, 64);
            l[r] = l[r] * corr + ps;
            #pragma unroll
            for (int vf = 0; vf < 4; ++vf) oacc[vf][r] *= corr;
        }

        // P -> LDS (bf16, same swizzle); each wave owns rows w*16..+15
        #pragma unroll
        for (int cf = 0; cf < 4; ++cf) {
            #pragma unroll
            for (int r = 0; r < 4; ++r) {
                const int prow = w * 16 + g * 4 + r;
                const int pb = prow * 128 + (((cf * 16 + lr) * 2) ^ ((prow & 7) << 4));
                *reinterpret_cast<bf16_t*>(pt + pb) = (bf16_t)s[cf][r];
            }
        }

        // O += P V  (A = P rows of this wave, B = Vt rows = v channels)
        #pragma unroll
        for (int ms = 0; ms < 2; ++ms) {
            const int prow = w * 16 + lr;
            bf16x8 pa = *reinterpret_cast<const bf16x8*>(
                pt + prow * 128 + ((ms * 64 + 16 * g) ^ ((prow & 7) << 4)));
            #pragma unroll
            for (int vf = 0; vf < 4; ++vf) {
                const int vrow = vf * 16 + lr;
                bf16x8 vb = *reinterpret_cast<const bf16x8*>(
                    vt + vrow * 128 + ((ms * 64 + 16 * g) ^ ((vrow & 7) << 4)));
                oacc[vf] = __builtin_amdgcn_mfma_f32_16x16x32_bf16(pa, vb, oacc[vf], 0, 0, 0);
            }
        }
    }

    // epilogue: divide by row sums and store O
    #pragma unroll
    for (int vf = 0; vf < 4; ++vf) {
        #pragma unroll
        for (int r = 0; r < 4; ++r) {
            const int row = q0 + w * 16 + g * 4 + r;
            O[((size_t)b * NV + row) * 64 + vf * 16 + lr] = oacc[vf][r] / l[r];
        }
    }
}

// ---------------------------------------------------------------------------
// Kernel 3: output projection with the reinterpret-reshape gather:
// out[b][o][64a + r] = bo[o] + sum_c wo[o][c] * O[b][125c + a][r]
// One block per (b, a).
// ---------------------------------------------------------------------------
__global__ __launch_bounds__(256) void proj_kernel(
    const float* __restrict__ O, const float* __restrict__ wo,
    const float* __restrict__ bo, float* __restrict__ out)
{
    __shared__ float gl[64 * 64];   // [c][r]
    const int tid = threadIdx.x;
    const int b = blockIdx.x / QB;
    const int a = blockIdx.x % QB;

    #pragma unroll
    for (int it = 0; it < 4; ++it) {
        int i = tid + it * 256;
        int c = i >> 4, seg = i & 15;
        *reinterpret_cast<float4*>(&gl[c * 64 + seg * 4]) =
            *reinterpret_cast<const float4*>(&O[((size_t)b * NV + 125 * c + a) * 64 + seg * 4]);
    }
    __syncthreads();

    const int r = tid & 63;
    const int osub = __builtin_amdgcn_readfirstlane(threadIdx.x >> 6);

    float gcol[64];
    #pragma unroll
    for (int c = 0; c < 64; ++c) gcol[c] = gl[c * 64 + r];

    #pragma unroll 1
    for (int j = 0; j < 16; ++j) {
        const int o = osub * 16 + j;
        const float* __restrict__ wr = wo + o * 64;
        float acc = 0.f;
        #pragma unroll
        for (int c = 0; c < 64; ++c) acc = fmaf(wr[c], gcol[c], acc);
        out[((size_t)b * 64 + o) * NV + a * 64 + r] = acc + bo[o];
    }
}

// ---------------------------------------------------------------------------
extern "C" void kernel_launch(void* const* d_in, const int* in_sizes, int n_in,
                              void* d_out, int out_size, void* d_ws, size_t ws_size,
                              hipStream_t stream)
{
    const float* x  = (const float*)d_in[0];
    const float* wq = (const float*)d_in[1];
    const float* bq = (const float*)d_in[2];
    const float* wk = (const float*)d_in[3];
    const float* bk = (const float*)d_in[4];
    const float* wv = (const float*)d_in[5];
    const float* bv = (const float*)d_in[6];
    const float* wo = (const float*)d_in[7];
    const float* bo = (const float*)d_in[8];
    float* out = (float*)d_out;

    // workspace layout (bytes): Q 2,048,000 | K 2,048,000 | Vt 2,048,000 | O 4,096,000
    char* ws = (char*)d_ws;
    bf16_t* Q  = (bf16_t*)(ws);
    bf16_t* Kr = (bf16_t*)(ws + 2048000);
    bf16_t* Vt = (bf16_t*)(ws + 4096000);
    float*  O  = (float*) (ws + 6144000);

    qkv_kernel<<<dim3(2 * QB), dim3(256), 0, stream>>>(x, wq, bq, wk, bk, wv, bv, Q, Kr, Vt);
    attn_kernel<<<dim3(2 * QB), dim3(256), 0, stream>>>(Q, Kr, Vt, O);
    proj_kernel<<<dim3(2 * QB), dim3(256), 0, stream>>>(O, wo, bo, out);
}

// Round 3
// 206.322 us; speedup vs baseline: 1.8076x; 1.8076x over previous
//
#include <hip/hip_runtime.h>
#include <hip/hip_bf16.h>

typedef __bf16 bf16_t;
typedef __bf16 bf16x8 __attribute__((ext_vector_type(8)));
typedef float f32x4 __attribute__((ext_vector_type(4)));

#define NV 8000   // D*H*W
#define QB 125    // NV / 64

__device__ __forceinline__ bf16x8 cvt_bf16x8(const float* __restrict__ p) {
    float4 a = *reinterpret_cast<const float4*>(p);
    float4 b = *reinterpret_cast<const float4*>(p + 4);
    bf16x8 r;
    r[0] = (bf16_t)a.x; r[1] = (bf16_t)a.y; r[2] = (bf16_t)a.z; r[3] = (bf16_t)a.w;
    r[4] = (bf16_t)b.x; r[5] = (bf16_t)b.y; r[6] = (bf16_t)b.z; r[7] = (bf16_t)b.w;
    return r;
}

// ---------------------------------------------------------------------------
// Kernel 1: fused QKV 1x1x1 convs via MFMA.
// Per block (b, 64-voxel tile): A = x^T tile (voxel x chan, bf16 in LDS,
// XOR-swizzled), B = weight rows (natural [kout][c] layout -> B fragment).
// Q,K stored [n][k] bf16 (Q pre-scaled by 1/8*log2e); V transposed through
// LDS and stored Vt[v][n] bf16 with coalesced 16B stores.
// ---------------------------------------------------------------------------
__global__ __launch_bounds__(256) void qkv_kernel(
    const float* __restrict__ x,
    const float* __restrict__ wq, const float* __restrict__ bq,
    const float* __restrict__ wk, const float* __restrict__ bk,
    const float* __restrict__ wv, const float* __restrict__ bv,
    bf16_t* __restrict__ Q, bf16_t* __restrict__ Kr, bf16_t* __restrict__ Vt)
{
    __shared__ __align__(16) char xb[64 * 128];   // [voxel][chan] bf16, swizzled
    __shared__ __align__(16) char vl[64 * 128];   // [vout][voxel] bf16, swizzled

    const int tid = threadIdx.x;
    const int b  = blockIdx.x / QB;
    const int n0 = (blockIdx.x % QB) * 64;

    // stage x tile -> bf16 LDS (transpose during store)
    #pragma unroll
    for (int it = 0; it < 4; ++it) {
        int i = tid + it * 256;           // float4 index
        int c = i >> 4, seg = i & 15;
        float4 v4 = *reinterpret_cast<const float4*>(&x[((size_t)b * 64 + c) * NV + n0 + seg * 4]);
        #pragma unroll
        for (int j = 0; j < 4; ++j) {
            int vx = seg * 4 + j;
            *reinterpret_cast<bf16_t*>(xb + vx * 128 + ((c * 2) ^ ((vx & 7) << 4))) =
                (bf16_t)((&v4.x)[j]);
        }
    }
    __syncthreads();

    const int wid = tid >> 6;
    const int lane = tid & 63;
    const int g = lane >> 4;
    const int lr = lane & 15;
    const int mrow = wid * 16 + lr;       // A-fragment voxel row

    const bf16x8 xa0 = *reinterpret_cast<const bf16x8*>(
        xb + mrow * 128 + ((16 * g) ^ ((mrow & 7) << 4)));
    const bf16x8 xa1 = *reinterpret_cast<const bf16x8*>(
        xb + mrow * 128 + ((64 + 16 * g) ^ ((mrow & 7) << 4)));

    const f32x4 zero4 = {0.f, 0.f, 0.f, 0.f};
    const float QSCALE = 0.125f * 1.44269504088896f;

    // ---- Q ----
    #pragma unroll
    for (int nf = 0; nf < 4; ++nf) {
        const int kout = nf * 16 + lr;
        bf16x8 wb0 = cvt_bf16x8(wq + kout * 64 + 8 * g);
        bf16x8 wb1 = cvt_bf16x8(wq + kout * 64 + 32 + 8 * g);
        f32x4 acc = __builtin_amdgcn_mfma_f32_16x16x32_bf16(xa0, wb0, zero4, 0, 0, 0);
        acc = __builtin_amdgcn_mfma_f32_16x16x32_bf16(xa1, wb1, acc, 0, 0, 0);
        float bias = bq[kout];
        #pragma unroll
        for (int r = 0; r < 4; ++r) {
            int vox = wid * 16 + 4 * g + r;
            Q[((size_t)b * NV + n0 + vox) * 64 + kout] = (bf16_t)((acc[r] + bias) * QSCALE);
        }
    }
    // ---- K ----
    #pragma unroll
    for (int nf = 0; nf < 4; ++nf) {
        const int kout = nf * 16 + lr;
        bf16x8 wb0 = cvt_bf16x8(wk + kout * 64 + 8 * g);
        bf16x8 wb1 = cvt_bf16x8(wk + kout * 64 + 32 + 8 * g);
        f32x4 acc = __builtin_amdgcn_mfma_f32_16x16x32_bf16(xa0, wb0, zero4, 0, 0, 0);
        acc = __builtin_amdgcn_mfma_f32_16x16x32_bf16(xa1, wb1, acc, 0, 0, 0);
        float bias = bk[kout];
        #pragma unroll
        for (int r = 0; r < 4; ++r) {
            int vox = wid * 16 + 4 * g + r;
            Kr[((size_t)b * NV + n0 + vox) * 64 + kout] = (bf16_t)(acc[r] + bias);
        }
    }
    // ---- V (to LDS transpose, then coalesced store) ----
    #pragma unroll
    for (int nf = 0; nf < 4; ++nf) {
        const int vout = nf * 16 + lr;
        bf16x8 wb0 = cvt_bf16x8(wv + vout * 64 + 8 * g);
        bf16x8 wb1 = cvt_bf16x8(wv + vout * 64 + 32 + 8 * g);
        f32x4 acc = __builtin_amdgcn_mfma_f32_16x16x32_bf16(xa0, wb0, zero4, 0, 0, 0);
        acc = __builtin_amdgcn_mfma_f32_16x16x32_bf16(xa1, wb1, acc, 0, 0, 0);
        float bias = bv[vout];
        #pragma unroll
        for (int r = 0; r < 4; ++r) {
            int vox = wid * 16 + 4 * g + r;
            *reinterpret_cast<bf16_t*>(vl + vout * 128 + ((vox * 2) ^ ((vout & 7) << 4))) =
                (bf16_t)(acc[r] + bias);
        }
    }
    __syncthreads();
    // Vt writeback: 64 rows x 128 B = 512 16-B chunks -> 2 iterations of 256
    #pragma unroll
    for (int it = 0; it < 2; ++it) {
        int i = tid + it * 256;
        int row = i >> 3, ch = i & 7;
        uint4 val = *reinterpret_cast<const uint4*>(vl + row * 128 + ((ch * 16) ^ ((row & 7) << 4)));
        *reinterpret_cast<uint4*>(&Vt[((size_t)b * 64 + row) * NV + n0 + ch * 8]) = val;
    }
}

// ---------------------------------------------------------------------------
// Kernel 2: flash attention with split-K.  Grid = S * 2 * QB blocks.
// Each block: 64 Q rows, K-tiles [t0,t1).  Writes UNNORMALIZED partial O
// and per-row (m, l) for the combine pass.  Defer-max (THR=8, exp2 domain).
// ---------------------------------------------------------------------------
template<int S>
__global__ __launch_bounds__(256) void attn_kernel(
    const bf16_t* __restrict__ Q, const bf16_t* __restrict__ Kr,
    const bf16_t* __restrict__ Vt, float* __restrict__ Op, float* __restrict__ ml)
{
    __shared__ __align__(16) char kt[64 * 128];
    __shared__ __align__(16) char vt[64 * 128];
    __shared__ __align__(16) char pt[64 * 128];

    const int tid  = threadIdx.x;
    const int s    = blockIdx.x / (2 * QB);
    const int rem  = blockIdx.x % (2 * QB);
    const int b    = rem / QB;
    const int q0   = (rem % QB) * 64;
    const int t0   = (125 * s) / S;
    const int t1   = (125 * (s + 1)) / S;
    const int w    = tid >> 6;
    const int lane = tid & 63;
    const int g    = lane >> 4;
    const int lr   = lane & 15;

    bf16x8 qa0, qa1;
    {
        const size_t qbase = ((size_t)b * NV + q0 + w * 16 + lr) * 64;
        qa0 = *reinterpret_cast<const bf16x8*>(&Q[qbase + 8 * g]);
        qa1 = *reinterpret_cast<const bf16x8*>(&Q[qbase + 32 + 8 * g]);
    }

    const f32x4 zero4 = {0.f, 0.f, 0.f, 0.f};
    f32x4 oacc[4];
    float m[4], l[4];
    #pragma unroll
    for (int r = 0; r < 4; ++r) { m[r] = -1e30f; l[r] = 0.f; }
    #pragma unroll
    for (int vf = 0; vf < 4; ++vf) oacc[vf] = zero4;

    const size_t kbase = (size_t)b * NV * 64;
    const size_t vbase = (size_t)b * 64 * NV;

    for (int t = t0; t < t1; ++t) {
        const int m0 = t * 64;
        __syncthreads();
        #pragma unroll
        for (int it = 0; it < 2; ++it) {
            int i = tid + it * 256;
            int row = i >> 3, ch = i & 7;
            int dst = row * 128 + ((ch * 16) ^ ((row & 7) << 4));
            *reinterpret_cast<uint4*>(kt + dst) =
                *reinterpret_cast<const uint4*>(&Kr[kbase + (size_t)(m0 + row) * 64 + ch * 8]);
            *reinterpret_cast<uint4*>(vt + dst) =
                *reinterpret_cast<const uint4*>(&Vt[vbase + (size_t)row * NV + m0 + ch * 8]);
        }
        __syncthreads();

        // S = Q K^T
        f32x4 sf[4];
        #pragma unroll
        for (int cf = 0; cf < 4; ++cf) {
            const int row  = cf * 16 + lr;
            const int roff = row * 128;
            const int swz  = (row & 7) << 4;
            sf[cf] = __builtin_amdgcn_mfma_f32_16x16x32_bf16(
                qa0, *reinterpret_cast<const bf16x8*>(kt + roff + ((16 * g) ^ swz)),
                zero4, 0, 0, 0);
            sf[cf] = __builtin_amdgcn_mfma_f32_16x16x32_bf16(
                qa1, *reinterpret_cast<const bf16x8*>(kt + roff + ((64 + 16 * g) ^ swz)),
                sf[cf], 0, 0, 0);
        }

        // online softmax, exp2 domain, defer-max THR=8
        float mx[4];
        #pragma unroll
        for (int r = 0; r < 4; ++r) {
            mx[r] = fmaxf(fmaxf(sf[0][r], sf[1][r]), fmaxf(sf[2][r], sf[3][r]));
            #pragma unroll
            for (int off = 1; off < 16; off <<= 1)
                mx[r] = fmaxf(mx[r], __shfl_xor(mx[r], off, 64));
        }
        bool need = false;
        #pragma unroll
        for (int r = 0; r < 4; ++r) need |= (mx[r] > m[r] + 8.0f);
        if (__any(need)) {
            #pragma unroll
            for (int r = 0; r < 4; ++r) {
                const float mn = fmaxf(m[r], mx[r]);
                const float corr = exp2f(m[r] - mn);
                m[r] = mn;
                l[r] *= corr;
                #pragma unroll
                for (int vf = 0; vf < 4; ++vf) oacc[vf][r] *= corr;
            }
        }
        #pragma unroll
        for (int r = 0; r < 4; ++r) {
            float ps = 0.f;
            #pragma unroll
            for (int cf = 0; cf < 4; ++cf) {
                float p = exp2f(sf[cf][r] - m[r]);
                sf[cf][r] = p;
                ps += p;
            }
            #pragma unroll
            for (int off = 1; off < 16; off <<= 1)
                ps += __shfl_xor(ps, off, 64);
            l[r] += ps;
        }

        // P -> LDS (bf16, swizzled)
        #pragma unroll
        for (int cf = 0; cf < 4; ++cf) {
            #pragma unroll
            for (int r = 0; r < 4; ++r) {
                const int prow = w * 16 + g * 4 + r;
                const int pb = prow * 128 + (((cf * 16 + lr) * 2) ^ ((prow & 7) << 4));
                *reinterpret_cast<bf16_t*>(pt + pb) = (bf16_t)sf[cf][r];
            }
        }

        // O += P V
        #pragma unroll
        for (int ms = 0; ms < 2; ++ms) {
            const int prow = w * 16 + lr;
            bf16x8 pa = *reinterpret_cast<const bf16x8*>(
                pt + prow * 128 + ((ms * 64 + 16 * g) ^ ((prow & 7) << 4)));
            #pragma unroll
            for (int vf = 0; vf < 4; ++vf) {
                const int vrow = vf * 16 + lr;
                bf16x8 vb = *reinterpret_cast<const bf16x8*>(
                    vt + vrow * 128 + ((ms * 64 + 16 * g) ^ ((vrow & 7) << 4)));
                oacc[vf] = __builtin_amdgcn_mfma_f32_16x16x32_bf16(pa, vb, oacc[vf], 0, 0, 0);
            }
        }
    }

    // epilogue: unnormalized partial O + (m,l)
    const size_t obase = (size_t)(s * 2 + b) * NV;
    #pragma unroll
    for (int vf = 0; vf < 4; ++vf) {
        #pragma unroll
        for (int r = 0; r < 4; ++r) {
            const int row = q0 + w * 16 + g * 4 + r;
            Op[(obase + row) * 64 + vf * 16 + lr] = oacc[vf][r];
        }
    }
    if (lr == 0) {
        #pragma unroll
        for (int r = 0; r < 4; ++r) {
            const int row = q0 + w * 16 + g * 4 + r;
            ml[(obase + row) * 2]     = m[r];
            ml[(obase + row) * 2 + 1] = l[r];
        }
    }
}

// ---------------------------------------------------------------------------
// Kernel 2b: combine split-K partials.  O_final (into split-0 region) =
// sum_s exp2(m_s - M) * O_s / L,  L = sum_s l_s * exp2(m_s - M).
// ---------------------------------------------------------------------------
template<int S>
__global__ __launch_bounds__(256) void combine_kernel(
    float* __restrict__ Op, const float* __restrict__ ml)
{
    __shared__ float al[64 * 4];
    const int tid = threadIdx.x;
    const int b = blockIdx.x / QB;
    const int r0 = (blockIdx.x % QB) * 64;

    if (tid < 64) {
        const size_t row = r0 + tid;
        float M = -1e30f;
        #pragma unroll
        for (int s = 0; s < S; ++s)
            M = fmaxf(M, ml[((size_t)(s * 2 + b) * NV + row) * 2]);
        float L = 0.f;
        #pragma unroll
        for (int s = 0; s < S; ++s) {
            float a = exp2f(ml[((size_t)(s * 2 + b) * NV + row) * 2] - M);
            L += ml[((size_t)(s * 2 + b) * NV + row) * 2 + 1] * a;
            al[tid * 4 + s] = a;
        }
        const float inv = 1.0f / L;
        #pragma unroll
        for (int s = 0; s < S; ++s) al[tid * 4 + s] *= inv;
    }
    __syncthreads();

    #pragma unroll
    for (int it = 0; it < 4; ++it) {
        int i = tid + it * 256;
        int row = i >> 4, seg = i & 15;
        f32x4 acc = {0.f, 0.f, 0.f, 0.f};
        #pragma unroll
        for (int s = 0; s < S; ++s) {
            const float a = al[row * 4 + s];
            const f32x4 v = *reinterpret_cast<const f32x4*>(
                &Op[((size_t)(s * 2 + b) * NV + r0 + row) * 64 + seg * 4]);
            acc += a * v;
        }
        *reinterpret_cast<f32x4*>(&Op[((size_t)b * NV + r0 + row) * 64 + seg * 4]) = acc;
    }
}

// ---------------------------------------------------------------------------
// Kernel 3: output projection via MFMA.
// out[b][o][64a+r] = bo[o] + sum_c wo[o][c] * O[b][125c+a][r]
// A = wo (natural layout), B = G^T staged transposed in LDS.
// D: col = r (16 contiguous lanes -> 64B f32 stores), row = o.
// ---------------------------------------------------------------------------
__global__ __launch_bounds__(256) void proj_kernel(
    const float* __restrict__ O, const float* __restrict__ wo,
    const float* __restrict__ bo, float* __restrict__ out)
{
    __shared__ __align__(16) char glt[64 * 128];   // [r][c] bf16, swizzled
    const int tid = threadIdx.x;
    const int b = blockIdx.x / QB;
    const int a = blockIdx.x % QB;

    #pragma unroll
    for (int it = 0; it < 4; ++it) {
        int i = tid + it * 256;
        int c = i >> 4, seg = i & 15;
        float4 v4 = *reinterpret_cast<const float4*>(&O[((size_t)b * NV + 125 * c + a) * 64 + seg * 4]);
        #pragma unroll
        for (int j = 0; j < 4; ++j) {
            int r = seg * 4 + j;
            *reinterpret_cast<bf16_t*>(glt + r * 128 + ((c * 2) ^ ((r & 7) << 4))) =
                (bf16_t)((&v4.x)[j]);
        }
    }
    __syncthreads();

    const int wid = tid >> 6;
    const int lane = tid & 63;
    const int g = lane >> 4;
    const int lr = lane & 15;

    const int orow = wid * 16 + lr;
    const bf16x8 wa0 = cvt_bf16x8(wo + orow * 64 + 8 * g);
    const bf16x8 wa1 = cvt_bf16x8(wo + orow * 64 + 32 + 8 * g);

    float bo_r[4];
    #pragma unroll
    for (int r = 0; r < 4; ++r) bo_r[r] = bo[wid * 16 + 4 * g + r];

    const f32x4 zero4 = {0.f, 0.f, 0.f, 0.f};
    #pragma unroll
    for (int nf = 0; nf < 4; ++nf) {
        const int rrow = nf * 16 + lr;
        bf16x8 gb0 = *reinterpret_cast<const bf16x8*>(
            glt + rrow * 128 + ((16 * g) ^ ((rrow & 7) << 4)));
        bf16x8 gb1 = *reinterpret_cast<const bf16x8*>(
            glt + rrow * 128 + ((64 + 16 * g) ^ ((rrow & 7) << 4)));
        f32x4 acc = __builtin_amdgcn_mfma_f32_16x16x32_bf16(wa0, gb0, zero4, 0, 0, 0);
        acc = __builtin_amdgcn_mfma_f32_16x16x32_bf16(wa1, gb1, acc, 0, 0, 0);
        #pragma unroll
        for (int r = 0; r < 4; ++r) {
            const int o = wid * 16 + 4 * g + r;
            out[((size_t)b * 64 + o) * NV + a * 64 + nf * 16 + lr] = acc[r] + bo_r[r];
        }
    }
}

// ---------------------------------------------------------------------------
extern "C" void kernel_launch(void* const* d_in, const int* in_sizes, int n_in,
                              void* d_out, int out_size, void* d_ws, size_t ws_size,
                              hipStream_t stream)
{
    const float* x  = (const float*)d_in[0];
    const float* wq = (const float*)d_in[1];
    const float* bq = (const float*)d_in[2];
    const float* wk = (const float*)d_in[3];
    const float* bk = (const float*)d_in[4];
    const float* wv = (const float*)d_in[5];
    const float* bv = (const float*)d_in[6];
    const float* wo = (const float*)d_in[7];
    const float* bo = (const float*)d_in[8];
    float* out = (float*)d_out;

    // ws layout: Q(2,048,000) | K(2,048,000) | Vt(2,048,000) | Op(S*4,096,000) | ml(S*128,000)
    char* ws = (char*)d_ws;
    bf16_t* Q  = (bf16_t*)(ws);
    bf16_t* Kr = (bf16_t*)(ws + 2048000);
    bf16_t* Vt = (bf16_t*)(ws + 4096000);

    int S = 4;
    if (ws_size < 6144000ull + 4ull * 4224000ull) S = 2;
    if (ws_size < 6144000ull + 2ull * 4224000ull) S = 1;

    float* Op = (float*)(ws + 6144000);
    float* ml = (float*)(ws + 6144000 + (size_t)S * 4096000);

    qkv_kernel<<<dim3(2 * QB), dim3(256), 0, stream>>>(x, wq, bq, wk, bk, wv, bv, Q, Kr, Vt);

    if (S == 4) {
        attn_kernel<4><<<dim3(4 * 2 * QB), dim3(256), 0, stream>>>(Q, Kr, Vt, Op, ml);
        combine_kernel<4><<<dim3(2 * QB), dim3(256), 0, stream>>>(Op, ml);
    } else if (S == 2) {
        attn_kernel<2><<<dim3(2 * 2 * QB), dim3(256), 0, stream>>>(Q, Kr, Vt, Op, ml);
        combine_kernel<2><<<dim3(2 * QB), dim3(256), 0, stream>>>(Op, ml);
    } else {
        attn_kernel<1><<<dim3(1 * 2 * QB), dim3(256), 0, stream>>>(Q, Kr, Vt, Op, ml);
        combine_kernel<1><<<dim3(2 * QB), dim3(256), 0, stream>>>(Op, ml);
    }

    proj_kernel<<<dim3(2 * QB), dim3(256), 0, stream>>>(Op, wo, bo, out);
}